// Round 1
// baseline (203.895 us; speedup 1.0000x reference)
//
#include <hip/hip_runtime.h>

#define NUM_HEADS 16u

// ALiBi bias: out[((b*H + h)*S + i)*S + j] = -slopes[h] * |i - j|
// Pure write-bandwidth-bound: 1 GiB f32 out, ~64 B in.
// Strategy: flat grid-stride over float4 stores; 32-bit index math
// (out_size < 2^31); S read on-device (scalar input lives in device mem).
__global__ __launch_bounds__(256) void alibi_bias_kernel(
    const float* __restrict__ slopes,
    const int* __restrict__ seq_p,
    float* __restrict__ out,
    unsigned int n_total)
{
    const unsigned int S  = (unsigned int)seq_p[0];
    const unsigned int S4 = S >> 2;              // S assumed %4==0 (2048 here)
    const unsigned int n4 = n_total >> 2;
    const unsigned int stride = gridDim.x * blockDim.x;
    float4* __restrict__ out4 = (float4*)out;

    for (unsigned int v = blockIdx.x * blockDim.x + threadIdx.x; v < n4; v += stride) {
        unsigned int jv  = v % S4;               // vec4 index within row
        unsigned int row = v / S4;               // row = (b*H + h)*S + i
        unsigned int i   = row % S;
        unsigned int h   = (row / S) % NUM_HEADS;

        float nslope = -slopes[h];               // 16 floats, L1-resident
        int   ii = (int)i;
        int   j0 = (int)(jv << 2);

        float4 o;
        o.x = nslope * (float)abs(ii - j0);
        o.y = nslope * (float)abs(ii - (j0 + 1));
        o.z = nslope * (float)abs(ii - (j0 + 2));
        o.w = nslope * (float)abs(ii - (j0 + 3));
        out4[v] = o;
    }

    // Scalar tail for generality (no-op when n_total % 4 == 0).
    for (unsigned int e = (n4 << 2) + blockIdx.x * blockDim.x + threadIdx.x;
         e < n_total; e += stride) {
        unsigned int j   = e % S;
        unsigned int row = e / S;
        unsigned int i   = row % S;
        unsigned int h   = (row / S) % NUM_HEADS;
        out[e] = -slopes[h] * (float)abs((int)i - (int)j);
    }
}

extern "C" void kernel_launch(void* const* d_in, const int* in_sizes, int n_in,
                              void* d_out, int out_size, void* d_ws, size_t ws_size,
                              hipStream_t stream) {
    const float* slopes = (const float*)d_in[0];
    const int*   seq_p  = (const int*)d_in[1];
    float*       out    = (float*)d_out;

    unsigned int n  = (unsigned int)out_size;
    unsigned int n4 = n >> 2;

    const int block = 256;
    unsigned int blocks_needed = (n4 + block - 1) / block;
    unsigned int grid = blocks_needed < 2048u ? blocks_needed : 2048u;  // 8 blk/CU x 256 CU
    if (grid < 1u) grid = 1u;

    alibi_bias_kernel<<<dim3(grid), dim3(block), 0, stream>>>(slopes, seq_p, out, n);
}

// Round 3
// 201.127 us; speedup vs baseline: 1.0138x; 1.0138x over previous
//
#include <hip/hip_runtime.h>

#define NUM_HEADS 16u
#define CHUNK 2048u   // floats per block-iteration (8 KiB)

typedef float f32x4 __attribute__((ext_vector_type(4)));  // clang vector: OK for nontemporal builtins

// ALiBi bias: out[((b*H + h)*S + i)*S + j] = -slopes[h] * |i - j|
// Write-BW-bound (1 GiB f32 out, ~64 B in). Harness fill kernel measures the
// pure-write ceiling at ~6.5 TB/s; goal is to match it.
// Fast path (S % CHUNK == 0): one 2048-float row-chunk per block-iteration,
// all division hoisted to once per chunk; inner math is 3 f32 subs + 4 muls
// (abs via free VOP3 modifier) per float4; nontemporal dwordx4 stores.
__global__ __launch_bounds__(256) void alibi_bias_kernel(
    const float* __restrict__ slopes,
    const int* __restrict__ seq_p,
    float* __restrict__ out,
    unsigned int n_total)
{
    const unsigned int S = (unsigned int)seq_p[0];

    if ((S % CHUNK) == 0u) {                     // uniform branch (S=2048 here)
        const unsigned int nchunks = n_total / CHUNK;
        for (unsigned int c = blockIdx.x; c < nchunks; c += gridDim.x) {
            const unsigned int base = c * CHUNK;       // element index
            const unsigned int row  = base / S;        // once per 8 KiB
            const unsigned int jst  = base - row * S;  // chunk start within row
            const unsigned int i    = row % S;
            const unsigned int h    = (row / S) % NUM_HEADS;
            const float nslope = -slopes[h];

            // thread t covers float4 #t and #(t+256) of this chunk
            const int j0 = (int)(jst + (threadIdx.x << 2));
            float d0 = (float)((int)i - j0);           // exact in f32 (<2^24)
            f32x4* __restrict__ o4 =
                (f32x4*)(out + base) + threadIdx.x;

            f32x4 o;
            o.x = nslope * fabsf(d0);
            o.y = nslope * fabsf(d0 - 1.0f);
            o.z = nslope * fabsf(d0 - 2.0f);
            o.w = nslope * fabsf(d0 - 3.0f);
            __builtin_nontemporal_store(o, o4);

            const float d1 = d0 - 1024.0f;             // exact
            o.x = nslope * fabsf(d1);
            o.y = nslope * fabsf(d1 - 1.0f);
            o.z = nslope * fabsf(d1 - 2.0f);
            o.w = nslope * fabsf(d1 - 3.0f);
            __builtin_nontemporal_store(o, o4 + 256);
        }
        return;
    }

    // Generic slow path (any S): grid-stride scalar with per-element div/mod.
    const unsigned int stride = gridDim.x * blockDim.x;
    for (unsigned int e = blockIdx.x * blockDim.x + threadIdx.x;
         e < n_total; e += stride) {
        unsigned int j   = e % S;
        unsigned int row = e / S;
        unsigned int i   = row % S;
        unsigned int h   = (row / S) % NUM_HEADS;
        out[e] = -slopes[h] * (float)abs((int)i - (int)j);
    }
}

extern "C" void kernel_launch(void* const* d_in, const int* in_sizes, int n_in,
                              void* d_out, int out_size, void* d_ws, size_t ws_size,
                              hipStream_t stream) {
    const float* slopes = (const float*)d_in[0];
    const int*   seq_p  = (const int*)d_in[1];
    float*       out    = (float*)d_out;

    const unsigned int n = (unsigned int)out_size;

    const int block = 256;
    // Size grid for the fast path: one chunk per block-iteration.
    unsigned int nchunks = (n + CHUNK - 1) / CHUNK;
    unsigned int grid = nchunks < 16384u ? nchunks : 16384u;
    if (grid < 1u) grid = 1u;

    alibi_bias_kernel<<<dim3(grid), dim3(block), 0, stream>>>(slopes, seq_p, out, n);
}